// Round 2
// baseline (8404.494 us; speedup 1.0000x reference)
//
#include <hip/hip_runtime.h>

#define DINLINE __device__ __forceinline__

#define Bc 2
#define LENc 13294
#define Cc 256
#define NHc 8
#define NQc 300
#define Lc 6
#define FFc 1024

DINLINE float bf2f(unsigned short u) { return __uint_as_float(((unsigned)u) << 16); }
DINLINE unsigned short f2bf(float f) {
  unsigned u = __float_as_uint(f);
  return (unsigned short)((u + 0x7fffu + ((u >> 16) & 1u)) >> 16);
}
DINLINE float ldany(const void* p, size_t i, int isbf) {
  return isbf ? bf2f(((const unsigned short*)p)[i]) : ((const float*)p)[i];
}
DINLINE const void* pick(const void* base, size_t eoff, int isbf) {
  return (const void*)((const char*)base + (isbf ? eoff * 2 : eoff * 4));
}

// dtype detect: valid_ratios == 1.0 exactly. bf16 -> u16[0]=0x3F80; f32 LE -> u16[0]=0
__global__ void detect_kernel(const unsigned short* __restrict__ vr_raw, int* __restrict__ flag) {
  if (threadIdx.x == 0 && blockIdx.x == 0) flag[0] = (vr_raw[0] == 0x3F80) ? 1 : 0;
}

// GEMM: Y[M,N] = X[M,K] @ W[N,K]^T + bias, optional relu. W/bias native dtype, element offsets.
__global__ __launch_bounds__(256) void gemm_bias_kernel(
    const float* __restrict__ X, const void* __restrict__ Wbase, size_t weoff,
    const void* __restrict__ bbase, size_t beoff, float* __restrict__ Y,
    int M, int N, int K, int relu, const int* __restrict__ dflag) {
  const int isbf = dflag[0];
  const void* W = pick(Wbase, weoff, isbf);
  const void* bias = pick(bbase, beoff, isbf);
  __shared__ float As[16][64];
  __shared__ float Bs[16][64];
  const int tid = threadIdx.x;
  const int tx = tid & 15, ty = tid >> 4;
  const int m0 = blockIdx.y << 6, n0 = blockIdx.x << 6;
  const int lm = tid >> 2;
  const int lk = (tid & 3) << 2;
  float acc[4][4] = {};

  for (int kt = 0; kt < K; kt += 16) {
    int gm = m0 + lm;
    float4 a4 = make_float4(0.f, 0.f, 0.f, 0.f);
    if (gm < M) a4 = *(const float4*)(X + (size_t)gm * K + kt + lk);
    As[lk + 0][lm] = a4.x; As[lk + 1][lm] = a4.y;
    As[lk + 2][lm] = a4.z; As[lk + 3][lm] = a4.w;
    size_t woff = (size_t)(n0 + lm) * K + kt + lk;
    float w0, w1, w2, w3;
    if (isbf) {
      ushort4 w4 = *(const ushort4*)((const unsigned short*)W + woff);
      w0 = bf2f(w4.x); w1 = bf2f(w4.y); w2 = bf2f(w4.z); w3 = bf2f(w4.w);
    } else {
      float4 w4 = *(const float4*)((const float*)W + woff);
      w0 = w4.x; w1 = w4.y; w2 = w4.z; w3 = w4.w;
    }
    Bs[lk + 0][lm] = w0; Bs[lk + 1][lm] = w1;
    Bs[lk + 2][lm] = w2; Bs[lk + 3][lm] = w3;
    __syncthreads();
#pragma unroll
    for (int k = 0; k < 16; ++k) {
      float4 av = *(const float4*)(&As[k][ty << 2]);
      float4 bvv = *(const float4*)(&Bs[k][tx << 2]);
      float a[4] = {av.x, av.y, av.z, av.w};
      float b[4] = {bvv.x, bvv.y, bvv.z, bvv.w};
#pragma unroll
      for (int i = 0; i < 4; ++i)
#pragma unroll
        for (int j = 0; j < 4; ++j) acc[i][j] += a[i] * b[j];
    }
    __syncthreads();
  }
  float bv[4];
#pragma unroll
  for (int j = 0; j < 4; ++j) bv[j] = ldany(bias, n0 + (tx << 2) + j, isbf);
#pragma unroll
  for (int i = 0; i < 4; ++i) {
    int gm = m0 + (ty << 2) + i;
    if (gm >= M) continue;
    float4 o;
    o.x = acc[i][0] + bv[0]; o.y = acc[i][1] + bv[1];
    o.z = acc[i][2] + bv[2]; o.w = acc[i][3] + bv[3];
    if (relu) {
      o.x = fmaxf(o.x, 0.f); o.y = fmaxf(o.y, 0.f);
      o.z = fmaxf(o.z, 0.f); o.w = fmaxf(o.w, 0.f);
    }
    *(float4*)(Y + (size_t)gm * N + n0 + (tx << 2)) = o;
  }
}

__global__ void conv_in_kernel(const void* __restrict__ in, float* __restrict__ out,
                               int n, const int* __restrict__ dflag) {
  int i = blockIdx.x * 256 + threadIdx.x;
  if (i < n) out[i] = ldany(in, i, dflag[0]);
}
__global__ void store_out_kernel(const float* __restrict__ in, void* __restrict__ out,
                                 int n, const int* __restrict__ dflag) {
  int i = blockIdx.x * 256 + threadIdx.x;
  if (i >= n) return;
  if (dflag[0]) ((unsigned short*)out)[i] = f2bf(in[i]);
  else ((float*)out)[i] = in[i];
}
__global__ void add_any_kernel(const float* __restrict__ a, const void* __restrict__ b,
                               float* __restrict__ o, int n, const int* __restrict__ dflag) {
  int i = blockIdx.x * 256 + threadIdx.x;
  if (i < n) o[i] = a[i] + ldany(b, i, dflag[0]);
}
__global__ void add_bcast_kernel(const float* __restrict__ a, const float* __restrict__ qp,
                                 float* __restrict__ o, int n, int per) {
  int i = blockIdx.x * 256 + threadIdx.x;
  if (i < n) o[i] = a[i] + qp[i % per];
}

// residual + LayerNorm (row = 256); g/b native dtype with element offset
__global__ __launch_bounds__(256) void add_ln_kernel(
    float* __restrict__ resout, const float* __restrict__ x,
    const void* __restrict__ gbase, const void* __restrict__ bbase, size_t eoff,
    int M, const int* __restrict__ dflag) {
  const int isbf = dflag[0];
  const void* g = pick(gbase, eoff, isbf);
  const void* b = pick(bbase, eoff, isbf);
  int row = blockIdx.x;
  int t = threadIdx.x;
  if (row >= M) return;
  size_t base = (size_t)row * 256;
  float v = resout[base + t] + x[base + t];
  __shared__ float red[4];
  __shared__ float stat[2];
  int wid = t >> 6, lane = t & 63;
  float s = v;
#pragma unroll
  for (int o = 32; o > 0; o >>= 1) s += __shfl_down(s, o, 64);
  if (lane == 0) red[wid] = s;
  __syncthreads();
  if (t == 0) stat[0] = (red[0] + red[1] + red[2] + red[3]) * (1.f / 256.f);
  __syncthreads();
  float mean = stat[0];
  float d = v - mean;
  float s2 = d * d;
#pragma unroll
  for (int o = 32; o > 0; o >>= 1) s2 += __shfl_down(s2, o, 64);
  if (lane == 0) red[wid] = s2;
  __syncthreads();
  if (t == 0) stat[1] = (red[0] + red[1] + red[2] + red[3]) * (1.f / 256.f);
  __syncthreads();
  float rstd = rsqrtf(stat[1] + 1e-5f);
  resout[base + t] = d * rstd * ldany(g, t, isbf) + ldany(b, t, isbf);
}

__global__ void softmax16_kernel(float* __restrict__ aw, int total) {
  int i = blockIdx.x * 256 + threadIdx.x;
  if (i >= total) return;
  float* p = aw + (size_t)i * 16;
  float m = -1e30f;
#pragma unroll
  for (int k = 0; k < 16; ++k) m = fmaxf(m, p[k]);
  float e[16];
  float s = 0.f;
#pragma unroll
  for (int k = 0; k < 16; ++k) { e[k] = expf(p[k] - m); s += e[k]; }
  float inv = 1.f / s;
#pragma unroll
  for (int k = 0; k < 16; ++k) p[k] = e[k] * inv;
}

__global__ void enc_ref_kernel(const void* __restrict__ vr, float* __restrict__ ref,
                               const int* __restrict__ dflag) {
  const int isbf = dflag[0];
  int idx = blockIdx.x * 256 + threadIdx.x;
  if (idx >= Bc * LENc) return;
  int b = idx / LENc, p = idx % LENc;
  int st, HW, lvl;
  if (p < 10000)      { lvl = 0; st = 0;     HW = 100; }
  else if (p < 12500) { lvl = 1; st = 10000; HW = 50; }
  else if (p < 13125) { lvl = 2; st = 12500; HW = 25; }
  else                { lvl = 3; st = 13125; HW = 13; }
  int r = p - st;
  int i = r / HW, j = r % HW;
  float vrx = ldany(vr, (b * 4 + lvl) * 2 + 0, isbf);
  float vry = ldany(vr, (b * 4 + lvl) * 2 + 1, isbf);
  float ry = (i + 0.5f) / (vry * HW);
  float rx = (j + 0.5f) / (vrx * HW);
#pragma unroll
  for (int l = 0; l < 4; ++l) {
    ref[((size_t)idx * 4 + l) * 2 + 0] = rx * ldany(vr, (b * 4 + l) * 2 + 0, isbf);
    ref[((size_t)idx * 4 + l) * 2 + 1] = ry * ldany(vr, (b * 4 + l) * 2 + 1, isbf);
  }
}

__global__ void dec_ref_kernel(const void* __restrict__ qe, const void* __restrict__ rw,
                               const void* __restrict__ rb, const void* __restrict__ vr,
                               float* __restrict__ dref, const int* __restrict__ dflag) {
  const int isbf = dflag[0];
  int idx = blockIdx.x * 256 + threadIdx.x;
  if (idx >= NQc * 2) return;
  int qi = idx >> 1, c = idx & 1;
  float s = ldany(rb, c, isbf);
  for (int k = 0; k < 256; ++k)
    s += ldany(qe, (size_t)qi * 512 + k, isbf) * ldany(rw, c * 256 + k, isbf);
  s = 1.f / (1.f + expf(-s));
  for (int b = 0; b < Bc; ++b)
#pragma unroll
    for (int l = 0; l < 4; ++l)
      dref[(((size_t)(b * NQc + qi)) * 4 + l) * 2 + c] = s * ldany(vr, (b * 4 + l) * 2 + c, isbf);
}

__global__ void dec_init_kernel(const void* __restrict__ qe, float* __restrict__ qpos,
                                float* __restrict__ out, const int* __restrict__ dflag) {
  const int isbf = dflag[0];
  int i = blockIdx.x * 256 + threadIdx.x;
  if (i >= NQc * Cc) return;
  int qi = i >> 8, c = i & 255;
  qpos[i] = ldany(qe, (size_t)qi * 512 + c, isbf);
  float t = ldany(qe, (size_t)qi * 512 + 256 + c, isbf);
  out[i] = t;
  out[NQc * Cc + i] = t;
}

__global__ __launch_bounds__(256) void deform_sample_kernel(
    const float* __restrict__ ref, const float* __restrict__ off,
    const float* __restrict__ aw, const float* __restrict__ value,
    float* __restrict__ out, int Q) {
  int unit = blockIdx.x * 8 + (threadIdx.x >> 5);
  int d = threadIdx.x & 31;
  int h = unit & 7;
  int bq = unit >> 3;
  if (bq >= Bc * Q) return;
  int b = bq / Q;
  const int HWs[4] = {100, 50, 25, 13};
  const int starts[4] = {0, 10000, 12500, 13125};
  const float* refp = ref + (size_t)bq * 8;
  const float* offp = off + (size_t)bq * 256 + h * 32;
  const float* awp = aw + (size_t)bq * 128 + h * 16;
  const float* vbase = value + (size_t)b * LENc * 256 + h * 32 + d;
  float acc = 0.f;
#pragma unroll
  for (int l = 0; l < 4; ++l) {
    int HW = HWs[l];
    float HWf = (float)HW;
    int st = starts[l];
    float rx = refp[l * 2 + 0], ry = refp[l * 2 + 1];
#pragma unroll
    for (int p = 0; p < 4; ++p) {
      float ox = offp[(l * 4 + p) * 2 + 0];
      float oy = offp[(l * 4 + p) * 2 + 1];
      float a = awp[l * 4 + p];
      float x = rx * HWf + ox - 0.5f;
      float y = ry * HWf + oy - 0.5f;
      float xf = floorf(x), yf = floorf(y);
      float wx = x - xf, wy = y - yf;
      int x0 = (int)xf, y0 = (int)yf;
      float w00 = (1.f - wx) * (1.f - wy) * a;
      float w10 = wx * (1.f - wy) * a;
      float w01 = (1.f - wx) * wy * a;
      float w11 = wx * wy * a;
      bool xi0 = (x0 >= 0) & (x0 < HW);
      bool xi1 = (x0 + 1 >= 0) & (x0 + 1 < HW);
      bool yi0 = (y0 >= 0) & (y0 < HW);
      bool yi1 = (y0 + 1 >= 0) & (y0 + 1 < HW);
      if (xi0 & yi0) acc += w00 * vbase[(size_t)(st + y0 * HW + x0) * 256];
      if (xi1 & yi0) acc += w10 * vbase[(size_t)(st + y0 * HW + x0 + 1) * 256];
      if (xi0 & yi1) acc += w01 * vbase[(size_t)(st + (y0 + 1) * HW + x0) * 256];
      if (xi1 & yi1) acc += w11 * vbase[(size_t)(st + (y0 + 1) * HW + x0 + 1) * 256];
    }
  }
  out[(size_t)bq * 256 + h * 32 + d] = acc;
}

__global__ __launch_bounds__(256) void mha_core_kernel(
    const float* __restrict__ qk, const float* __restrict__ v, float* __restrict__ out) {
  __shared__ float sc[4][304];
  int wslot = threadIdx.x >> 6;
  int lane = threadIdx.x & 63;
  int w = blockIdx.x * 4 + wslot;
  if (w >= Bc * NHc * NQc) return;
  int b = w / (NHc * NQc);
  int rem = w % (NHc * NQc);
  int h = rem / NQc;
  int qi = rem % NQc;
  const float scale = 0.1767766952966369f;
  float qv[32];
  const float* qptr = qk + ((size_t)(b * NQc + qi)) * 512 + h * 32;
#pragma unroll
  for (int d = 0; d < 32; ++d) qv[d] = qptr[d];
  float mx = -1e30f;
  for (int j = lane; j < NQc; j += 64) {
    const float* kptr = qk + ((size_t)(b * NQc + j)) * 512 + 256 + h * 32;
    float s = 0.f;
#pragma unroll
    for (int d = 0; d < 32; ++d) s += qv[d] * kptr[d];
    s *= scale;
    sc[wslot][j] = s;
    mx = fmaxf(mx, s);
  }
#pragma unroll
  for (int o = 32; o > 0; o >>= 1) mx = fmaxf(mx, __shfl_xor(mx, o, 64));
  float se = 0.f;
  for (int j = lane; j < NQc; j += 64) {
    float e = expf(sc[wslot][j] - mx);
    sc[wslot][j] = e;
    se += e;
  }
#pragma unroll
  for (int o = 32; o > 0; o >>= 1) se += __shfl_xor(se, o, 64);
  float inv = 1.f / se;
  if (lane < 32) {
    int d = lane;
    float acc = 0.f;
    for (int j = 0; j < NQc; ++j)
      acc += sc[wslot][j] * v[((size_t)(b * NQc + j)) * 256 + h * 32 + d];
    out[((size_t)(b * NQc + qi)) * 256 + h * 32 + d] = acc * inv;
  }
}

static inline int cdiv_i(int a, int b) { return (a + b - 1) / b; }

extern "C" void kernel_launch(void* const* d_in, const int* in_sizes, int n_in,
                              void* d_out, int out_size, void* d_ws, size_t ws_size,
                              hipStream_t stream) {
  (void)in_sizes; (void)n_in;
  const void* src_p = d_in[0];
  const void* pos_p = d_in[1];
  const void* qe_p = d_in[2];
  const void* vr_p = d_in[3];
  const void* e_off_w = d_in[4];  const void* e_off_b = d_in[5];
  const void* e_aw_w = d_in[6];   const void* e_aw_b = d_in[7];
  const void* e_val_w = d_in[8];  const void* e_val_b = d_in[9];
  const void* e_out_w = d_in[10]; const void* e_out_b = d_in[11];
  const void* e_f1_w = d_in[12];  const void* e_f1_b = d_in[13];
  const void* e_f2_w = d_in[14];  const void* e_f2_b = d_in[15];
  const void* d_sa_in_w = d_in[16];  const void* d_sa_in_b = d_in[17];
  const void* d_sa_out_w = d_in[18]; const void* d_sa_out_b = d_in[19];
  const void* d_off_w = d_in[20]; const void* d_off_b = d_in[21];
  const void* d_aw_w = d_in[22];  const void* d_aw_b = d_in[23];
  const void* d_val_w = d_in[24]; const void* d_val_b = d_in[25];
  const void* d_out_w = d_in[26]; const void* d_out_b = d_in[27];
  const void* d_f1_w = d_in[28];  const void* d_f1_b = d_in[29];
  const void* d_f2_w = d_in[30];  const void* d_f2_b = d_in[31];
  const void* ref_w = d_in[32];   const void* ref_b = d_in[33];
  const void* e_ln1_g = d_in[34]; const void* e_ln1_b = d_in[35];
  const void* e_ln2_g = d_in[36]; const void* e_ln2_b = d_in[37];
  const void* d_ln1_g = d_in[38]; const void* d_ln1_b = d_in[39];
  const void* d_ln2_g = d_in[40]; const void* d_ln2_b = d_in[41];
  const void* d_ln3_g = d_in[42]; const void* d_ln3_b = d_in[43];

  const size_t BLC = (size_t)Bc * LENc * Cc;
  const size_t BIG = (size_t)Bc * LENc * FFc;
  int* dflag = (int*)d_ws;
  float* ws = (float*)d_ws + 16;
  float* mem = ws;
  float* bufA = mem + BLC;
  float* big = bufA + BLC;
  float* value = big;
  float* offb = big + BLC;
  float* awb = big + 2 * BLC;
  float* attnb = awb + (size_t)Bc * LENc * 128;
  float* encref = big + BIG;
  float* qpos = encref + (size_t)Bc * LENc * 8;
  float* doutb = qpos + (size_t)NQc * Cc;
  float* qbuf = doutb + (size_t)Bc * NQc * Cc;
  float* qkb = qbuf + (size_t)Bc * NQc * Cc;
  float* dvb = qkb + (size_t)Bc * NQc * 512;
  float* dattn = dvb + (size_t)Bc * NQc * Cc;
  float* drefb = dattn + (size_t)Bc * NQc * Cc;
  float* doffb = drefb + (size_t)Bc * NQc * 8;
  float* dawb = doffb + (size_t)Bc * NQc * Cc;
  float* dhid = dawb + (size_t)Bc * NQc * 128;
  float* dproj = dhid + (size_t)Bc * NQc * FFc;
  size_t total_f = (size_t)(dproj + (size_t)Bc * NQc * Cc - (float*)d_ws);
  if (ws_size < total_f * sizeof(float)) return;

  const int Mrows = Bc * LENc;
  const int Mdec = Bc * NQc;
  const int ELT_BLK = 256;

  auto gemm = [&](const float* Xp, const void* Wp, size_t we, const void* bp, size_t be,
                  float* Yp, int M, int N, int K, int relu) {
    dim3 g(N / 64, cdiv_i(M, 64));
    gemm_bias_kernel<<<g, dim3(256), 0, stream>>>(Xp, Wp, we, bp, be, Yp, M, N, K, relu, dflag);
  };
  auto addln = [&](float* res, const float* x, const void* g, const void* b, size_t eoff, int M) {
    add_ln_kernel<<<M, 256, 0, stream>>>(res, x, g, b, eoff, M, dflag);
  };

  detect_kernel<<<1, 1, 0, stream>>>((const unsigned short*)vr_p, dflag);
  conv_in_kernel<<<cdiv_i((int)BLC, ELT_BLK), ELT_BLK, 0, stream>>>(src_p, mem, (int)BLC, dflag);
  enc_ref_kernel<<<cdiv_i(Bc * LENc, ELT_BLK), ELT_BLK, 0, stream>>>(vr_p, encref, dflag);

  for (int i = 0; i < Lc; ++i) {
    size_t o256 = (size_t)i * 256, o128 = (size_t)i * 128, o1024 = (size_t)i * 1024;
    size_t oW = (size_t)i * 256 * 256, oAW = (size_t)i * 128 * 256, oF = (size_t)i * 1024 * 256;
    add_any_kernel<<<cdiv_i((int)BLC, ELT_BLK), ELT_BLK, 0, stream>>>(mem, pos_p, bufA, (int)BLC, dflag);
    gemm(bufA, e_off_w, oW, e_off_b, o256, offb, Mrows, 256, 256, 0);
    gemm(bufA, e_aw_w, oAW, e_aw_b, o128, awb, Mrows, 128, 256, 0);
    softmax16_kernel<<<cdiv_i(Mrows * NHc, ELT_BLK), ELT_BLK, 0, stream>>>(awb, Mrows * NHc);
    gemm(mem, e_val_w, oW, e_val_b, o256, value, Mrows, 256, 256, 0);
    deform_sample_kernel<<<Mrows, 256, 0, stream>>>(encref, offb, awb, value, attnb, LENc);
    gemm(attnb, e_out_w, oW, e_out_b, o256, bufA, Mrows, 256, 256, 0);
    addln(mem, bufA, e_ln1_g, e_ln1_b, o256, Mrows);
    gemm(mem, e_f1_w, oF, e_f1_b, o1024, big, Mrows, 1024, 256, 1);
    gemm(big, e_f2_w, oF, e_f2_b, o256, bufA, Mrows, 256, 1024, 0);
    addln(mem, bufA, e_ln2_g, e_ln2_b, o256, Mrows);
  }

  dec_init_kernel<<<cdiv_i(NQc * Cc, ELT_BLK), ELT_BLK, 0, stream>>>(qe_p, qpos, doutb, dflag);
  dec_ref_kernel<<<cdiv_i(NQc * 2, ELT_BLK), ELT_BLK, 0, stream>>>(qe_p, ref_w, ref_b, vr_p, drefb, dflag);

  const int ndec = Mdec * Cc;
  for (int i = 0; i < Lc; ++i) {
    size_t o256 = (size_t)i * 256, o128 = (size_t)i * 128, o1024 = (size_t)i * 1024, o768 = (size_t)i * 768;
    size_t oW = (size_t)i * 256 * 256, oAW = (size_t)i * 128 * 256, oF = (size_t)i * 1024 * 256;
    size_t oSA = (size_t)i * 768 * 256;
    add_bcast_kernel<<<cdiv_i(ndec, ELT_BLK), ELT_BLK, 0, stream>>>(doutb, qpos, qbuf, ndec, NQc * Cc);
    gemm(qbuf, d_sa_in_w, oSA, d_sa_in_b, o768, qkb, Mdec, 512, 256, 0);
    gemm(doutb, d_sa_in_w, oSA + (size_t)512 * 256, d_sa_in_b, o768 + 512, dvb, Mdec, 256, 256, 0);
    mha_core_kernel<<<Bc * NHc * NQc / 4, 256, 0, stream>>>(qkb, dvb, dattn);
    gemm(dattn, d_sa_out_w, oW, d_sa_out_b, o256, dproj, Mdec, 256, 256, 0);
    addln(doutb, dproj, d_ln2_g, d_ln2_b, o256, Mdec);
    add_bcast_kernel<<<cdiv_i(ndec, ELT_BLK), ELT_BLK, 0, stream>>>(doutb, qpos, qbuf, ndec, NQc * Cc);
    gemm(qbuf, d_off_w, oW, d_off_b, o256, doffb, Mdec, 256, 256, 0);
    gemm(qbuf, d_aw_w, oAW, d_aw_b, o128, dawb, Mdec, 128, 256, 0);
    softmax16_kernel<<<cdiv_i(Mdec * NHc, ELT_BLK), ELT_BLK, 0, stream>>>(dawb, Mdec * NHc);
    gemm(mem, d_val_w, oW, d_val_b, o256, value, Mrows, 256, 256, 0);
    deform_sample_kernel<<<Mdec * NHc / 8, 256, 0, stream>>>(drefb, doffb, dawb, value, dattn, NQc);
    gemm(dattn, d_out_w, oW, d_out_b, o256, dproj, Mdec, 256, 256, 0);
    addln(doutb, dproj, d_ln1_g, d_ln1_b, o256, Mdec);
    gemm(doutb, d_f1_w, oF, d_f1_b, o1024, dhid, Mdec, 1024, 256, 1);
    gemm(dhid, d_f2_w, oF, d_f2_b, o256, dproj, Mdec, 256, 1024, 0);
    addln(doutb, dproj, d_ln3_g, d_ln3_b, o256, Mdec);
  }

  store_out_kernel<<<cdiv_i(out_size, ELT_BLK), ELT_BLK, 0, stream>>>(doutb, d_out, out_size, dflag);
}

// Round 4
// 3424.388 us; speedup vs baseline: 2.4543x; 2.4543x over previous
//
#include <hip/hip_runtime.h>

#define DINLINE __device__ __forceinline__

#define Bc 2
#define LENc 13294
#define Cc 256
#define NHc 8
#define NQc 300
#define Lc 6
#define FFc 1024

typedef unsigned short u16;
typedef __attribute__((ext_vector_type(8))) short bshort8;
typedef __attribute__((ext_vector_type(4))) float f32x4;

DINLINE float bf2f(u16 u) { return __uint_as_float(((unsigned)u) << 16); }
DINLINE u16 f2bf(float f) {
  unsigned u = __float_as_uint(f);
  return (u16)((u + 0x7fffu + ((u >> 16) & 1u)) >> 16);
}

// ============ packed f32 -> bf16 weight conversion ============
struct WPack {
  const float* src[14];
  int off4[15];  // prefix offsets in units of 4 elements
};
__global__ void convert_weights_kernel(WPack p, u16* __restrict__ dst) {
  int i4 = blockIdx.x * 256 + threadIdx.x;
  if (i4 >= p.off4[14]) return;
  int t = 0;
#pragma unroll
  for (int k = 0; k < 13; ++k) t += (i4 >= p.off4[k + 1]) ? 1 : 0;
  int local = i4 - p.off4[t];
  float4 v = *(const float4*)(p.src[t] + (size_t)local * 4);
  ushort4 o;
  o.x = f2bf(v.x); o.y = f2bf(v.y); o.z = f2bf(v.z); o.w = f2bf(v.w);
  *(ushort4*)(dst + (size_t)i4 * 4) = o;
}

// ============ MFMA GEMM ============
// Y[M,N] = X[M,K](bf16) @ W[N,K](bf16)^T + bias(f32)
// flags: bit0 = relu, bit1 = write bf16 to Yb (else f32 to Yf)
// Tile 128x128, BK=32, 256 threads = 4 waves (2x2 of 64x64 per-wave tiles).
__global__ __launch_bounds__(256) void gemm_mfma_kernel(
    const u16* __restrict__ X, const u16* __restrict__ W, const float* __restrict__ bias,
    float* __restrict__ Yf, u16* __restrict__ Yb, int M, int N, int K, int flags) {
  __shared__ __align__(16) u16 lds[8256];
  const int tid = threadIdx.x;
  const int m0 = blockIdx.y << 7, n0 = blockIdx.x << 7;
  const int w = tid >> 6, l = tid & 63;
  const int wm = (w & 1) << 6, wn = (w >> 1) << 6;
  const int lane15 = l & 15, quad = l >> 4;
  const int r_ = tid >> 2;   // 0..63
  const int q_ = tid & 3;    // k-chunk
  f32x4 acc[4][4] = {};

  for (int kt = 0; kt < K; kt += 32) {
#pragma unroll
    for (int it = 0; it < 2; ++it) {
      int r = r_ + (it << 6);
      int gm = m0 + r; if (gm >= M) gm = M - 1;  // dup-load, store guarded
      const u16* sa = X + (size_t)gm * K + kt + q_ * 8;
      ushort4 a0 = *(const ushort4*)sa;
      ushort4 a1 = *(const ushort4*)(sa + 4);
      u16* da = &lds[q_ * 1032 + r * 8];
      *(ushort4*)da = a0; *(ushort4*)(da + 4) = a1;
      int gn = n0 + r;
      const u16* sb = W + (size_t)gn * K + kt + q_ * 8;
      ushort4 b0 = *(const ushort4*)sb;
      ushort4 b1 = *(const ushort4*)(sb + 4);
      u16* db = &lds[4128 + q_ * 1032 + r * 8];
      *(ushort4*)db = b0; *(ushort4*)(db + 4) = b1;
    }
    __syncthreads();
    bshort8 af[4], bfr[4];
#pragma unroll
    for (int mi = 0; mi < 4; ++mi)
      af[mi] = *(const bshort8*)&lds[quad * 1032 + (wm + mi * 16 + lane15) * 8];
#pragma unroll
    for (int ni = 0; ni < 4; ++ni)
      bfr[ni] = *(const bshort8*)&lds[4128 + quad * 1032 + (wn + ni * 16 + lane15) * 8];
#pragma unroll
    for (int mi = 0; mi < 4; ++mi)
#pragma unroll
      for (int ni = 0; ni < 4; ++ni)
        acc[mi][ni] = __builtin_amdgcn_mfma_f32_16x16x32_bf16(af[mi], bfr[ni], acc[mi][ni], 0, 0, 0);
    __syncthreads();
  }

  float bv[4];
#pragma unroll
  for (int ni = 0; ni < 4; ++ni) bv[ni] = bias[n0 + wn + ni * 16 + lane15];
  const int relu = flags & 1, asbf = flags & 2;
#pragma unroll
  for (int mi = 0; mi < 4; ++mi)
#pragma unroll
    for (int reg = 0; reg < 4; ++reg) {
      int gm = m0 + wm + mi * 16 + quad * 4 + reg;
      if (gm >= M) continue;
#pragma unroll
      for (int ni = 0; ni < 4; ++ni) {
        float v = acc[mi][ni][reg] + bv[ni];
        if (relu) v = fmaxf(v, 0.f);
        int gc = n0 + wn + ni * 16 + lane15;
        if (asbf) Yb[(size_t)gm * N + gc] = f2bf(v);
        else Yf[(size_t)gm * N + gc] = v;
      }
    }
}

// ============ elementwise ============
__global__ void conv_in_kernel(const float* __restrict__ in, float* __restrict__ outf,
                               u16* __restrict__ outb, int n) {
  int i = blockIdx.x * 256 + threadIdx.x;
  if (i < n) { float v = in[i]; outf[i] = v; outb[i] = f2bf(v); }
}
__global__ void store_f32_kernel(const float* __restrict__ in, float* __restrict__ out, int n) {
  int i = blockIdx.x * 256 + threadIdx.x;
  if (i < n) out[i] = in[i];
}
__global__ void add_pos_kernel(const float* __restrict__ a, const float* __restrict__ b,
                               u16* __restrict__ o, int n) {
  int i = blockIdx.x * 256 + threadIdx.x;
  if (i < n) o[i] = f2bf(a[i] + b[i]);
}
__global__ void add_bcast_bf_kernel(const float* __restrict__ a, const float* __restrict__ qp,
                                    u16* __restrict__ o, int n, int per) {
  int i = blockIdx.x * 256 + threadIdx.x;
  if (i < n) o[i] = f2bf(a[i] + qp[i % per]);
}

// residual += x; LN; write f32 residual + bf16 shadow. g/b f32.
__global__ __launch_bounds__(256) void add_ln_kernel(
    float* __restrict__ resout, const float* __restrict__ x,
    const float* __restrict__ g, const float* __restrict__ b,
    u16* __restrict__ shadow, int M) {
  int row = blockIdx.x;
  int t = threadIdx.x;
  if (row >= M) return;
  size_t base = (size_t)row * 256;
  float v = resout[base + t] + x[base + t];
  __shared__ float red[4];
  __shared__ float stat[2];
  int wid = t >> 6, lane = t & 63;
  float s = v;
#pragma unroll
  for (int o = 32; o > 0; o >>= 1) s += __shfl_down(s, o, 64);
  if (lane == 0) red[wid] = s;
  __syncthreads();
  if (t == 0) stat[0] = (red[0] + red[1] + red[2] + red[3]) * (1.f / 256.f);
  __syncthreads();
  float mean = stat[0];
  float d = v - mean;
  float s2 = d * d;
#pragma unroll
  for (int o = 32; o > 0; o >>= 1) s2 += __shfl_down(s2, o, 64);
  if (lane == 0) red[wid] = s2;
  __syncthreads();
  if (t == 0) stat[1] = (red[0] + red[1] + red[2] + red[3]) * (1.f / 256.f);
  __syncthreads();
  float rstd = rsqrtf(stat[1] + 1e-5f);
  float y = d * rstd * g[t] + b[t];
  resout[base + t] = y;
  shadow[base + t] = f2bf(y);
}

__global__ void softmax16_kernel(float* __restrict__ aw, int total) {
  int i = blockIdx.x * 256 + threadIdx.x;
  if (i >= total) return;
  float* p = aw + (size_t)i * 16;
  float m = -1e30f;
#pragma unroll
  for (int k = 0; k < 16; ++k) m = fmaxf(m, p[k]);
  float e[16];
  float s = 0.f;
#pragma unroll
  for (int k = 0; k < 16; ++k) { e[k] = expf(p[k] - m); s += e[k]; }
  float inv = 1.f / s;
#pragma unroll
  for (int k = 0; k < 16; ++k) p[k] = e[k] * inv;
}

__global__ void enc_ref_kernel(const float* __restrict__ vr, float* __restrict__ ref) {
  int idx = blockIdx.x * 256 + threadIdx.x;
  if (idx >= Bc * LENc) return;
  int b = idx / LENc, p = idx % LENc;
  int st, HW, lvl;
  if (p < 10000)      { lvl = 0; st = 0;     HW = 100; }
  else if (p < 12500) { lvl = 1; st = 10000; HW = 50; }
  else if (p < 13125) { lvl = 2; st = 12500; HW = 25; }
  else                { lvl = 3; st = 13125; HW = 13; }
  int r = p - st;
  int i = r / HW, j = r % HW;
  float vrx = vr[(b * 4 + lvl) * 2 + 0];
  float vry = vr[(b * 4 + lvl) * 2 + 1];
  float ry = (i + 0.5f) / (vry * HW);
  float rx = (j + 0.5f) / (vrx * HW);
#pragma unroll
  for (int l = 0; l < 4; ++l) {
    ref[((size_t)idx * 4 + l) * 2 + 0] = rx * vr[(b * 4 + l) * 2 + 0];
    ref[((size_t)idx * 4 + l) * 2 + 1] = ry * vr[(b * 4 + l) * 2 + 1];
  }
}

__global__ void dec_ref_kernel(const float* __restrict__ qe, const float* __restrict__ rw,
                               const float* __restrict__ rb, const float* __restrict__ vr,
                               float* __restrict__ dref) {
  int idx = blockIdx.x * 256 + threadIdx.x;
  if (idx >= NQc * 2) return;
  int qi = idx >> 1, c = idx & 1;
  float s = rb[c];
  for (int k = 0; k < 256; ++k)
    s += qe[(size_t)qi * 512 + k] * rw[c * 256 + k];
  s = 1.f / (1.f + expf(-s));
  for (int b = 0; b < Bc; ++b)
#pragma unroll
    for (int l = 0; l < 4; ++l)
      dref[(((size_t)(b * NQc + qi)) * 4 + l) * 2 + c] = s * vr[(b * 4 + l) * 2 + c];
}

__global__ void dec_init_kernel(const float* __restrict__ qe, float* __restrict__ qpos,
                                float* __restrict__ outf, u16* __restrict__ outb) {
  int i = blockIdx.x * 256 + threadIdx.x;
  if (i >= NQc * Cc) return;
  int qi = i >> 8, c = i & 255;
  qpos[i] = qe[(size_t)qi * 512 + c];
  float t = qe[(size_t)qi * 512 + 256 + c];
  outf[i] = t;
  outf[NQc * Cc + i] = t;
  outb[i] = f2bf(t);
  outb[NQc * Cc + i] = f2bf(t);
}

// ============ deformable sampler ============
// 8 lanes per (b,q,h); lane c4 handles channels 4*c4..4*c4+3. value/out bf16.
__global__ __launch_bounds__(256) void deform_sample_kernel(
    const float* __restrict__ ref, const float* __restrict__ off,
    const float* __restrict__ aw, const u16* __restrict__ value,
    u16* __restrict__ out, int Q) {
  int g = blockIdx.x * 256 + threadIdx.x;
  int unit = g >> 3;
  int c4 = g & 7;
  int h = unit & 7;
  int bq = unit >> 3;
  if (bq >= Bc * Q) return;
  int b = bq / Q;
  const int HWs[4] = {100, 50, 25, 13};
  const int starts[4] = {0, 10000, 12500, 13125};
  const float* refp = ref + (size_t)bq * 8;
  const float* offp = off + (size_t)bq * 256 + h * 32;
  const float* awp = aw + (size_t)bq * 128 + h * 16;
  const u16* vbase = value + (size_t)b * LENc * 256 + h * 32 + c4 * 4;
  float a0 = 0.f, a1 = 0.f, a2 = 0.f, a3 = 0.f;
#pragma unroll
  for (int l = 0; l < 4; ++l) {
    int HW = HWs[l];
    float HWf = (float)HW;
    int st = starts[l];
    float rx = refp[l * 2 + 0], ry = refp[l * 2 + 1];
#pragma unroll
    for (int p = 0; p < 4; ++p) {
      float ox = offp[(l * 4 + p) * 2 + 0];
      float oy = offp[(l * 4 + p) * 2 + 1];
      float a = awp[l * 4 + p];
      float x = rx * HWf + ox - 0.5f;
      float y = ry * HWf + oy - 0.5f;
      float xf = floorf(x), yf = floorf(y);
      float wx = x - xf, wy = y - yf;
      int x0 = (int)xf, y0 = (int)yf;
      float w00 = (1.f - wx) * (1.f - wy) * a;
      float w10 = wx * (1.f - wy) * a;
      float w01 = (1.f - wx) * wy * a;
      float w11 = wx * wy * a;
      bool xi0 = (x0 >= 0) & (x0 < HW);
      bool xi1 = (x0 + 1 >= 0) & (x0 + 1 < HW);
      bool yi0 = (y0 >= 0) & (y0 < HW);
      bool yi1 = (y0 + 1 >= 0) & (y0 + 1 < HW);
      if (xi0 & yi0) {
        ushort4 s = *(const ushort4*)(vbase + (size_t)(st + y0 * HW + x0) * 256);
        a0 += w00 * bf2f(s.x); a1 += w00 * bf2f(s.y); a2 += w00 * bf2f(s.z); a3 += w00 * bf2f(s.w);
      }
      if (xi1 & yi0) {
        ushort4 s = *(const ushort4*)(vbase + (size_t)(st + y0 * HW + x0 + 1) * 256);
        a0 += w10 * bf2f(s.x); a1 += w10 * bf2f(s.y); a2 += w10 * bf2f(s.z); a3 += w10 * bf2f(s.w);
      }
      if (xi0 & yi1) {
        ushort4 s = *(const ushort4*)(vbase + (size_t)(st + (y0 + 1) * HW + x0) * 256);
        a0 += w01 * bf2f(s.x); a1 += w01 * bf2f(s.y); a2 += w01 * bf2f(s.z); a3 += w01 * bf2f(s.w);
      }
      if (xi1 & yi1) {
        ushort4 s = *(const ushort4*)(vbase + (size_t)(st + (y0 + 1) * HW + x0 + 1) * 256);
        a0 += w11 * bf2f(s.x); a1 += w11 * bf2f(s.y); a2 += w11 * bf2f(s.z); a3 += w11 * bf2f(s.w);
      }
    }
  }
  ushort4 o;
  o.x = f2bf(a0); o.y = f2bf(a1); o.z = f2bf(a2); o.w = f2bf(a3);
  *(ushort4*)(out + (size_t)bq * 256 + h * 32 + c4 * 4) = o;
}

// ============ decoder self-attention core ============
__global__ __launch_bounds__(256) void mha_core_kernel(
    const float* __restrict__ qk, const float* __restrict__ v, u16* __restrict__ out) {
  __shared__ float sc[4][304];
  int wslot = threadIdx.x >> 6;
  int lane = threadIdx.x & 63;
  int w = blockIdx.x * 4 + wslot;
  if (w >= Bc * NHc * NQc) return;
  int b = w / (NHc * NQc);
  int rem = w % (NHc * NQc);
  int h = rem / NQc;
  int qi = rem % NQc;
  const float scale = 0.1767766952966369f;
  float qv[32];
  const float* qptr = qk + ((size_t)(b * NQc + qi)) * 512 + h * 32;
#pragma unroll
  for (int d = 0; d < 32; ++d) qv[d] = qptr[d];
  float mx = -1e30f;
  for (int j = lane; j < NQc; j += 64) {
    const float* kptr = qk + ((size_t)(b * NQc + j)) * 512 + 256 + h * 32;
    float s = 0.f;
#pragma unroll
    for (int d = 0; d < 32; ++d) s += qv[d] * kptr[d];
    s *= scale;
    sc[wslot][j] = s;
    mx = fmaxf(mx, s);
  }
#pragma unroll
  for (int o = 32; o > 0; o >>= 1) mx = fmaxf(mx, __shfl_xor(mx, o, 64));
  float se = 0.f;
  for (int j = lane; j < NQc; j += 64) {
    float e = expf(sc[wslot][j] - mx);
    sc[wslot][j] = e;
    se += e;
  }
#pragma unroll
  for (int o = 32; o > 0; o >>= 1) se += __shfl_xor(se, o, 64);
  float inv = 1.f / se;
  if (lane < 32) {
    int d = lane;
    float acc = 0.f;
    for (int j = 0; j < NQc; ++j)
      acc += sc[wslot][j] * v[((size_t)(b * NQc + j)) * 256 + h * 32 + d];
    out[((size_t)(b * NQc + qi)) * 256 + h * 32 + d] = f2bf(acc * inv);
  }
}

// ============ host ============
static inline int cdiv_i(int a, int b) { return (a + b - 1) / b; }

// bf16 weight-pack element offsets
#define WE_OFF   0
#define WE_AW    393216
#define WE_VAL   589824
#define WE_OUT   983040
#define WE_F1    1376256
#define WE_F2    2949120
#define WD_SAIN  4521984
#define WD_SAOUT 5701632
#define WD_OFF   6094848
#define WD_AW    6488064
#define WD_VAL   6684672
#define WD_OUT   7077888
#define WD_F1    7471104
#define WD_F2    9043968
#define W_TOTAL  10616832

extern "C" void kernel_launch(void* const* d_in, const int* in_sizes, int n_in,
                              void* d_out, int out_size, void* d_ws, size_t ws_size,
                              hipStream_t stream) {
  (void)in_sizes; (void)n_in;
  const float* src_p = (const float*)d_in[0];
  const float* pos_p = (const float*)d_in[1];
  const float* qe_p = (const float*)d_in[2];
  const float* vr_p = (const float*)d_in[3];
  const float* e_off_w = (const float*)d_in[4];  const float* e_off_b = (const float*)d_in[5];
  const float* e_aw_w = (const float*)d_in[6];   const float* e_aw_b = (const float*)d_in[7];
  const float* e_val_w = (const float*)d_in[8];  const float* e_val_b = (const float*)d_in[9];
  const float* e_out_w = (const float*)d_in[10]; const float* e_out_b = (const float*)d_in[11];
  const float* e_f1_w = (const float*)d_in[12];  const float* e_f1_b = (const float*)d_in[13];
  const float* e_f2_w = (const float*)d_in[14];  const float* e_f2_b = (const float*)d_in[15];
  const float* d_sa_in_w = (const float*)d_in[16];  const float* d_sa_in_b = (const float*)d_in[17];
  const float* d_sa_out_w = (const float*)d_in[18]; const float* d_sa_out_b = (const float*)d_in[19];
  const float* d_off_w = (const float*)d_in[20]; const float* d_off_b = (const float*)d_in[21];
  const float* d_aw_w = (const float*)d_in[22];  const float* d_aw_b = (const float*)d_in[23];
  const float* d_val_w = (const float*)d_in[24]; const float* d_val_b = (const float*)d_in[25];
  const float* d_out_w = (const float*)d_in[26]; const float* d_out_b = (const float*)d_in[27];
  const float* d_f1_w = (const float*)d_in[28];  const float* d_f1_b = (const float*)d_in[29];
  const float* d_f2_w = (const float*)d_in[30];  const float* d_f2_b = (const float*)d_in[31];
  const float* ref_w = (const float*)d_in[32];   const float* ref_b = (const float*)d_in[33];
  const float* e_ln1_g = (const float*)d_in[34]; const float* e_ln1_b = (const float*)d_in[35];
  const float* e_ln2_g = (const float*)d_in[36]; const float* e_ln2_b = (const float*)d_in[37];
  const float* d_ln1_g = (const float*)d_in[38]; const float* d_ln1_b = (const float*)d_in[39];
  const float* d_ln2_g = (const float*)d_in[40]; const float* d_ln2_b = (const float*)d_in[41];
  const float* d_ln3_g = (const float*)d_in[42]; const float* d_ln3_b = (const float*)d_in[43];

  const size_t BLC = (size_t)Bc * LENc * Cc;  // 6,806,528
  float* ws = (float*)d_ws;

  // f32 buffers
  float* mem = ws;                       // BLC
  float* bufA = mem + BLC;               // BLC
  float* U = bufA + BLC;                 // union region: 2.5*BLC floats
  float* encref = U + (5 * BLC / 2);
  float* qpos = encref + (size_t)Bc * LENc * 8;
  float* doutb = qpos + (size_t)NQc * Cc;
  float* qkb = doutb + (size_t)Bc * NQc * Cc;
  float* dvb = qkb + (size_t)Bc * NQc * 512;
  float* drefb = dvb + (size_t)Bc * NQc * Cc;
  float* doffb = drefb + (size_t)Bc * NQc * 8;
  float* dawb = doffb + (size_t)Bc * NQc * Cc;
  float* dproj = dawb + (size_t)Bc * NQc * 128;
  float* after = dproj + (size_t)Bc * NQc * Cc;
  // bf16 buffers
  u16* mem_bf = (u16*)after;
  u16* qbuf_bf = mem_bf + BLC;
  u16* dout_bf = qbuf_bf + (size_t)Bc * NQc * Cc;
  u16* dattn_bf = dout_bf + (size_t)Bc * NQc * Cc;
  u16* dhid_bf = dattn_bf + (size_t)Bc * NQc * Cc;
  u16* wbf = dhid_bf + (size_t)Bc * NQc * FFc;   // converted weights
  u16* bf_end = wbf + W_TOTAL;
  // union members (attention phase)
  float* offb = U;                                  // BLC f32
  float* awb = U + BLC;                             // BLC/2 f32
  u16* value_bf = (u16*)(U + 3 * BLC / 2);          // BLC u16
  u16* xattn_bf = (u16*)(U + 2 * BLC);              // BLC u16
  // union member (encoder FFN phase)
  u16* hid_bf = (u16*)U;                            // 2*BLC floats worth

  size_t total_bytes = (size_t)((char*)bf_end - (char*)d_ws);
  if (ws_size < total_bytes) return;

  const int Mrows = Bc * LENc;  // 26588
  const int Mdec = Bc * NQc;    // 600
  const int EB = 256;

  // ---- convert all weights to bf16 (single packed kernel) ----
  WPack wp;
  wp.src[0] = e_off_w;   wp.src[1] = e_aw_w;    wp.src[2] = e_val_w;  wp.src[3] = e_out_w;
  wp.src[4] = e_f1_w;    wp.src[5] = e_f2_w;    wp.src[6] = d_sa_in_w; wp.src[7] = d_sa_out_w;
  wp.src[8] = d_off_w;   wp.src[9] = d_aw_w;    wp.src[10] = d_val_w; wp.src[11] = d_out_w;
  wp.src[12] = d_f1_w;   wp.src[13] = d_f2_w;
  const int offs[15] = {WE_OFF, WE_AW, WE_VAL, WE_OUT, WE_F1, WE_F2, WD_SAIN, WD_SAOUT,
                        WD_OFF, WD_AW, WD_VAL, WD_OUT, WD_F1, WD_F2, W_TOTAL};
  for (int k = 0; k < 15; ++k) wp.off4[k] = offs[k] / 4;
  convert_weights_kernel<<<cdiv_i(W_TOTAL / 4, EB), EB, 0, stream>>>(wp, wbf);

  auto gemm = [&](const u16* Xp, const u16* Wp, const float* bp, float* Yf, u16* Yb,
                  int M, int N, int K, int flags) {
    dim3 g(N / 128, cdiv_i(M, 128));
    gemm_mfma_kernel<<<g, dim3(256), 0, stream>>>(Xp, Wp, bp, Yf, Yb, M, N, K, flags);
  };

  conv_in_kernel<<<cdiv_i((int)BLC, EB), EB, 0, stream>>>(src_p, mem, mem_bf, (int)BLC);
  enc_ref_kernel<<<cdiv_i(Bc * LENc, EB), EB, 0, stream>>>(vr_p, encref);

  // ---- encoder ----
  for (int i = 0; i < Lc; ++i) {
    const size_t oW = (size_t)i * 256 * 256, oAW = (size_t)i * 128 * 256, oF = (size_t)i * 1024 * 256;
    const size_t o256 = (size_t)i * 256, o128 = (size_t)i * 128, o1024 = (size_t)i * 1024;
    add_pos_kernel<<<cdiv_i((int)BLC, EB), EB, 0, stream>>>(mem, pos_p, xattn_bf, (int)BLC);
    gemm(xattn_bf, wbf + WE_OFF + oW, e_off_b + o256, offb, nullptr, Mrows, 256, 256, 0);
    gemm(xattn_bf, wbf + WE_AW + oAW, e_aw_b + o128, awb, nullptr, Mrows, 128, 256, 0);
    softmax16_kernel<<<cdiv_i(Mrows * NHc, EB), EB, 0, stream>>>(awb, Mrows * NHc);
    gemm(mem_bf, wbf + WE_VAL + oW, e_val_b + o256, nullptr, value_bf, Mrows, 256, 256, 2);
    deform_sample_kernel<<<cdiv_i(Mrows * NHc * 8, EB), EB, 0, stream>>>(
        encref, offb, awb, value_bf, xattn_bf, LENc);
    gemm(xattn_bf, wbf + WE_OUT + oW, e_out_b + o256, bufA, nullptr, Mrows, 256, 256, 0);
    add_ln_kernel<<<Mrows, 256, 0, stream>>>(mem, bufA, e_ln1_g + o256, e_ln1_b + o256, mem_bf, Mrows);
    gemm(mem_bf, wbf + WE_F1 + oF, e_f1_b + o1024, nullptr, hid_bf, Mrows, 1024, 256, 3);
    gemm(hid_bf, wbf + WE_F2 + oF, e_f2_b + o256, bufA, nullptr, Mrows, 256, 1024, 0);
    add_ln_kernel<<<Mrows, 256, 0, stream>>>(mem, bufA, e_ln2_g + o256, e_ln2_b + o256, mem_bf, Mrows);
  }

  // ---- decoder prep ----
  dec_init_kernel<<<cdiv_i(NQc * Cc, EB), EB, 0, stream>>>(qe_p, qpos, doutb, dout_bf);
  dec_ref_kernel<<<cdiv_i(NQc * 2, EB), EB, 0, stream>>>(qe_p, ref_w, ref_b, vr_p, drefb);

  const int ndec = Mdec * Cc;
  for (int i = 0; i < Lc; ++i) {
    const size_t oW = (size_t)i * 256 * 256, oAW = (size_t)i * 128 * 256, oF = (size_t)i * 1024 * 256;
    const size_t oSA = (size_t)i * 768 * 256;
    const size_t o256 = (size_t)i * 256, o128 = (size_t)i * 128, o1024 = (size_t)i * 1024, o768 = (size_t)i * 768;
    // self-attention
    add_bcast_bf_kernel<<<cdiv_i(ndec, EB), EB, 0, stream>>>(doutb, qpos, qbuf_bf, ndec, NQc * Cc);
    gemm(qbuf_bf, wbf + WD_SAIN + oSA, d_sa_in_b + o768, qkb, nullptr, Mdec, 512, 256, 0);
    gemm(dout_bf, wbf + WD_SAIN + oSA + (size_t)512 * 256, d_sa_in_b + o768 + 512, dvb, nullptr, Mdec, 256, 256, 0);
    mha_core_kernel<<<Bc * NHc * NQc / 4, 256, 0, stream>>>(qkb, dvb, dattn_bf);
    gemm(dattn_bf, wbf + WD_SAOUT + oW, d_sa_out_b + o256, dproj, nullptr, Mdec, 256, 256, 0);
    add_ln_kernel<<<Mdec, 256, 0, stream>>>(doutb, dproj, d_ln2_g + o256, d_ln2_b + o256, dout_bf, Mdec);
    // cross (deformable) attention
    add_bcast_bf_kernel<<<cdiv_i(ndec, EB), EB, 0, stream>>>(doutb, qpos, qbuf_bf, ndec, NQc * Cc);
    gemm(qbuf_bf, wbf + WD_OFF + oW, d_off_b + o256, doffb, nullptr, Mdec, 256, 256, 0);
    gemm(qbuf_bf, wbf + WD_AW + oAW, d_aw_b + o128, dawb, nullptr, Mdec, 128, 256, 0);
    softmax16_kernel<<<cdiv_i(Mdec * NHc, EB), EB, 0, stream>>>(dawb, Mdec * NHc);
    gemm(mem_bf, wbf + WD_VAL + oW, d_val_b + o256, nullptr, value_bf, Mrows, 256, 256, 2);
    deform_sample_kernel<<<cdiv_i(Mdec * NHc * 8, EB), EB, 0, stream>>>(
        drefb, doffb, dawb, value_bf, dattn_bf, NQc);
    gemm(dattn_bf, wbf + WD_OUT + oW, d_out_b + o256, dproj, nullptr, Mdec, 256, 256, 0);
    add_ln_kernel<<<Mdec, 256, 0, stream>>>(doutb, dproj, d_ln1_g + o256, d_ln1_b + o256, dout_bf, Mdec);
    // FFN
    gemm(dout_bf, wbf + WD_F1 + oF, d_f1_b + o1024, nullptr, dhid_bf, Mdec, 1024, 256, 3);
    gemm(dhid_bf, wbf + WD_F2 + oF, d_f2_b + o256, dproj, nullptr, Mdec, 256, 1024, 0);
    add_ln_kernel<<<Mdec, 256, 0, stream>>>(doutb, dproj, d_ln3_g + o256, d_ln3_b + o256, dout_bf, Mdec);
  }

  store_f32_kernel<<<cdiv_i(out_size, EB), EB, 0, stream>>>(doutb, (float*)d_out, out_size);
}

// Round 5
// 3189.226 us; speedup vs baseline: 2.6353x; 1.0737x over previous
//
#include <hip/hip_runtime.h>

#define DINLINE __device__ __forceinline__

#define Bc 2
#define LENc 13294
#define Cc 256
#define NHc 8
#define NQc 300
#define Lc 6
#define FFc 1024

typedef unsigned short u16;
typedef __attribute__((ext_vector_type(8))) short bshort8;
typedef __attribute__((ext_vector_type(8))) unsigned short ushort8v;
typedef __attribute__((ext_vector_type(4))) float f32x4;

DINLINE float bf2f(u16 u) { return __uint_as_float(((unsigned)u) << 16); }
DINLINE u16 f2bf(float f) {
  unsigned u = __float_as_uint(f);
  return (u16)((u + 0x7fffu + ((u >> 16) & 1u)) >> 16);
}
DINLINE void glds16(const u16* g, u16* l) {
  __builtin_amdgcn_global_load_lds((const __attribute__((address_space(1))) void*)g,
                                   (__attribute__((address_space(3))) void*)l, 16, 0, 0);
}

// ============ packed f32 -> bf16 weight conversion ============
struct WPack {
  const float* src[14];
  int off4[15];
};
__global__ void convert_weights_kernel(WPack p, u16* __restrict__ dst) {
  int i4 = blockIdx.x * 256 + threadIdx.x;
  if (i4 >= p.off4[14]) return;
  int t = 0;
#pragma unroll
  for (int k = 0; k < 13; ++k) t += (i4 >= p.off4[k + 1]) ? 1 : 0;
  int local = i4 - p.off4[t];
  float4 v = *(const float4*)(p.src[t] + (size_t)local * 4);
  ushort4 o;
  o.x = f2bf(v.x); o.y = f2bf(v.y); o.z = f2bf(v.z); o.w = f2bf(v.w);
  *(ushort4*)(dst + (size_t)i4 * 4) = o;
}

// ============ MFMA GEMM 128x128 (global_load_lds staging) ============
// Y[M,N] = X[M,K](bf16) @ W[N,K](bf16)^T + bias(f32)
// flags: bit0 relu, bit1 write bf16 to Yb (else f32 to Yf). N%128==0, K%32==0.
__global__ __launch_bounds__(256) void gemm_mfma_kernel(
    const u16* __restrict__ X, const u16* __restrict__ W, const float* __restrict__ bias,
    float* __restrict__ Yf, u16* __restrict__ Yb, int M, int N, int K, int flags) {
  __shared__ __align__(16) u16 lds[8256];  // A: 4 chunks x 2064B, B same at +8256B/2
  const int tid = threadIdx.x;
  const int m0 = blockIdx.y << 7, n0 = blockIdx.x << 7;
  const int w = tid >> 6, lane = tid & 63;
  const int wm = (w & 1) << 6, wn = (w >> 1) << 6;
  const int lane15 = lane & 15, quad = lane >> 4;
  f32x4 acc[4][4] = {};

  int gmA0 = m0 + lane;       if (gmA0 >= M) gmA0 = M - 1;
  int gmA1 = m0 + 64 + lane;  if (gmA1 >= M) gmA1 = M - 1;
  const u16* xa0 = X + (size_t)gmA0 * K + w * 8;
  const u16* xa1 = X + (size_t)gmA1 * K + w * 8;
  const u16* wb0 = W + (size_t)(n0 + lane) * K + w * 8;
  const u16* wb1 = W + (size_t)(n0 + 64 + lane) * K + w * 8;
  u16* la0 = &lds[w * 1032];
  u16* la1 = &lds[w * 1032 + 512];
  u16* lb0 = &lds[4128 + w * 1032];
  u16* lb1 = &lds[4128 + w * 1032 + 512];

  for (int kt = 0; kt < K; kt += 32) {
    glds16(xa0 + kt, la0);
    glds16(xa1 + kt, la1);
    glds16(wb0 + kt, lb0);
    glds16(wb1 + kt, lb1);
    __syncthreads();
    bshort8 af[4], bfr[4];
#pragma unroll
    for (int mi = 0; mi < 4; ++mi)
      af[mi] = *(const bshort8*)&lds[quad * 1032 + (wm + mi * 16 + lane15) * 8];
#pragma unroll
    for (int ni = 0; ni < 4; ++ni)
      bfr[ni] = *(const bshort8*)&lds[4128 + quad * 1032 + (wn + ni * 16 + lane15) * 8];
#pragma unroll
    for (int mi = 0; mi < 4; ++mi)
#pragma unroll
      for (int ni = 0; ni < 4; ++ni)
        acc[mi][ni] = __builtin_amdgcn_mfma_f32_16x16x32_bf16(af[mi], bfr[ni], acc[mi][ni], 0, 0, 0);
    __syncthreads();
  }

  float bv[4];
#pragma unroll
  for (int ni = 0; ni < 4; ++ni) bv[ni] = bias[n0 + wn + ni * 16 + lane15];
  const int relu = flags & 1, asbf = flags & 2;
#pragma unroll
  for (int mi = 0; mi < 4; ++mi)
#pragma unroll
    for (int reg = 0; reg < 4; ++reg) {
      int gm = m0 + wm + mi * 16 + quad * 4 + reg;
      if (gm >= M) continue;
#pragma unroll
      for (int ni = 0; ni < 4; ++ni) {
        float v = acc[mi][ni][reg] + bv[ni];
        if (relu) v = fmaxf(v, 0.f);
        int gc = n0 + wn + ni * 16 + lane15;
        if (asbf) Yb[(size_t)gm * N + gc] = f2bf(v);
        else Yf[(size_t)gm * N + gc] = v;
      }
    }
}

// ============ MFMA GEMM 64x64 (small M, decoder) ============
// N%64==0, K%32==0. 4 waves: 2x2 of 32x32.
__global__ __launch_bounds__(256) void gemm_small_kernel(
    const u16* __restrict__ X, const u16* __restrict__ W, const float* __restrict__ bias,
    float* __restrict__ Yf, u16* __restrict__ Yb, int M, int N, int K, int flags) {
  __shared__ __align__(16) u16 lds[4160];  // A: 4 chunks x 1040B = 2080 u16, B same
  const int tid = threadIdx.x;
  const int m0 = blockIdx.y << 6, n0 = blockIdx.x << 6;
  const int w = tid >> 6, lane = tid & 63;
  const int wm = (w & 1) << 5, wn = (w >> 1) << 5;
  const int lane15 = lane & 15, quad = lane >> 4;
  f32x4 acc[2][2] = {};

  int gmA = m0 + lane; if (gmA >= M) gmA = M - 1;
  const u16* xa = X + (size_t)gmA * K + w * 8;
  const u16* wb = W + (size_t)(n0 + lane) * K + w * 8;
  u16* la = &lds[w * 520];
  u16* lb = &lds[2080 + w * 520];

  for (int kt = 0; kt < K; kt += 32) {
    glds16(xa + kt, la);
    glds16(wb + kt, lb);
    __syncthreads();
    bshort8 af[2], bfr[2];
#pragma unroll
    for (int mi = 0; mi < 2; ++mi)
      af[mi] = *(const bshort8*)&lds[quad * 520 + (wm + mi * 16 + lane15) * 8];
#pragma unroll
    for (int ni = 0; ni < 2; ++ni)
      bfr[ni] = *(const bshort8*)&lds[2080 + quad * 520 + (wn + ni * 16 + lane15) * 8];
#pragma unroll
    for (int mi = 0; mi < 2; ++mi)
#pragma unroll
      for (int ni = 0; ni < 2; ++ni)
        acc[mi][ni] = __builtin_amdgcn_mfma_f32_16x16x32_bf16(af[mi], bfr[ni], acc[mi][ni], 0, 0, 0);
    __syncthreads();
  }

  float bv[2];
#pragma unroll
  for (int ni = 0; ni < 2; ++ni) bv[ni] = bias[n0 + wn + ni * 16 + lane15];
  const int relu = flags & 1, asbf = flags & 2;
#pragma unroll
  for (int mi = 0; mi < 2; ++mi)
#pragma unroll
    for (int reg = 0; reg < 4; ++reg) {
      int gm = m0 + wm + mi * 16 + quad * 4 + reg;
      if (gm >= M) continue;
#pragma unroll
      for (int ni = 0; ni < 2; ++ni) {
        float v = acc[mi][ni][reg] + bv[ni];
        if (relu) v = fmaxf(v, 0.f);
        int gc = n0 + wn + ni * 16 + lane15;
        if (asbf) Yb[(size_t)gm * N + gc] = f2bf(v);
        else Yf[(size_t)gm * N + gc] = v;
      }
    }
}

// ============ elementwise ============
__global__ void conv_in_kernel(const float* __restrict__ in, float* __restrict__ outf,
                               u16* __restrict__ outb, int n) {
  int i = blockIdx.x * 256 + threadIdx.x;
  if (i < n) { float v = in[i]; outf[i] = v; outb[i] = f2bf(v); }
}
__global__ void store_f32_kernel(const float* __restrict__ in, float* __restrict__ out, int n) {
  int i = blockIdx.x * 256 + threadIdx.x;
  if (i < n) out[i] = in[i];
}
__global__ void add_pos_kernel(const float* __restrict__ a, const float* __restrict__ b,
                               u16* __restrict__ o, int n) {
  int i = blockIdx.x * 256 + threadIdx.x;
  if (i < n) o[i] = f2bf(a[i] + b[i]);
}
__global__ void add_bcast_bf_kernel(const float* __restrict__ a, const float* __restrict__ qp,
                                    u16* __restrict__ o, int n, int per) {
  int i = blockIdx.x * 256 + threadIdx.x;
  if (i < n) o[i] = f2bf(a[i] + qp[i % per]);
}

// residual += x; LN; write f32 residual + bf16 shadow
__global__ __launch_bounds__(256) void add_ln_kernel(
    float* __restrict__ resout, const float* __restrict__ x,
    const float* __restrict__ g, const float* __restrict__ b,
    u16* __restrict__ shadow, int M) {
  int row = blockIdx.x;
  int t = threadIdx.x;
  if (row >= M) return;
  size_t base = (size_t)row * 256;
  float v = resout[base + t] + x[base + t];
  __shared__ float red[4];
  __shared__ float stat[2];
  int wid = t >> 6, lane = t & 63;
  float s = v;
#pragma unroll
  for (int o = 32; o > 0; o >>= 1) s += __shfl_down(s, o, 64);
  if (lane == 0) red[wid] = s;
  __syncthreads();
  if (t == 0) stat[0] = (red[0] + red[1] + red[2] + red[3]) * (1.f / 256.f);
  __syncthreads();
  float mean = stat[0];
  float d = v - mean;
  float s2 = d * d;
#pragma unroll
  for (int o = 32; o > 0; o >>= 1) s2 += __shfl_down(s2, o, 64);
  if (lane == 0) red[wid] = s2;
  __syncthreads();
  if (t == 0) stat[1] = (red[0] + red[1] + red[2] + red[3]) * (1.f / 256.f);
  __syncthreads();
  float rstd = rsqrtf(stat[1] + 1e-5f);
  float y = d * rstd * g[t] + b[t];
  resout[base + t] = y;
  shadow[base + t] = f2bf(y);
}

__global__ void softmax16_kernel(float* __restrict__ aw, int total) {
  int i = blockIdx.x * 256 + threadIdx.x;
  if (i >= total) return;
  float* p = aw + (size_t)i * 16;
  float m = -1e30f;
#pragma unroll
  for (int k = 0; k < 16; ++k) m = fmaxf(m, p[k]);
  float e[16];
  float s = 0.f;
#pragma unroll
  for (int k = 0; k < 16; ++k) { e[k] = expf(p[k] - m); s += e[k]; }
  float inv = 1.f / s;
#pragma unroll
  for (int k = 0; k < 16; ++k) p[k] = e[k] * inv;
}

__global__ void enc_ref_kernel(const float* __restrict__ vr, float* __restrict__ ref) {
  int idx = blockIdx.x * 256 + threadIdx.x;
  if (idx >= Bc * LENc) return;
  int b = idx / LENc, p = idx % LENc;
  int st, HW, lvl;
  if (p < 10000)      { lvl = 0; st = 0;     HW = 100; }
  else if (p < 12500) { lvl = 1; st = 10000; HW = 50; }
  else if (p < 13125) { lvl = 2; st = 12500; HW = 25; }
  else                { lvl = 3; st = 13125; HW = 13; }
  int r = p - st;
  int i = r / HW, j = r % HW;
  float vrx = vr[(b * 4 + lvl) * 2 + 0];
  float vry = vr[(b * 4 + lvl) * 2 + 1];
  float ry = (i + 0.5f) / (vry * HW);
  float rx = (j + 0.5f) / (vrx * HW);
#pragma unroll
  for (int l = 0; l < 4; ++l) {
    ref[((size_t)idx * 4 + l) * 2 + 0] = rx * vr[(b * 4 + l) * 2 + 0];
    ref[((size_t)idx * 4 + l) * 2 + 1] = ry * vr[(b * 4 + l) * 2 + 1];
  }
}

__global__ void dec_ref_kernel(const float* __restrict__ qe, const float* __restrict__ rw,
                               const float* __restrict__ rb, const float* __restrict__ vr,
                               float* __restrict__ dref) {
  int idx = blockIdx.x * 256 + threadIdx.x;
  if (idx >= NQc * 2) return;
  int qi = idx >> 1, c = idx & 1;
  float s = rb[c];
  for (int k = 0; k < 256; ++k)
    s += qe[(size_t)qi * 512 + k] * rw[c * 256 + k];
  s = 1.f / (1.f + expf(-s));
  for (int b = 0; b < Bc; ++b)
#pragma unroll
    for (int l = 0; l < 4; ++l)
      dref[(((size_t)(b * NQc + qi)) * 4 + l) * 2 + c] = s * vr[(b * 4 + l) * 2 + c];
}

__global__ void dec_init_kernel(const float* __restrict__ qe, float* __restrict__ qpos,
                                float* __restrict__ outf, u16* __restrict__ outb) {
  int i = blockIdx.x * 256 + threadIdx.x;
  if (i >= NQc * Cc) return;
  int qi = i >> 8, c = i & 255;
  qpos[i] = qe[(size_t)qi * 512 + c];
  float t = qe[(size_t)qi * 512 + 256 + c];
  outf[i] = t;
  outf[NQc * Cc + i] = t;
  outb[i] = f2bf(t);
  outb[NQc * Cc + i] = f2bf(t);
}

// ============ deformable sampler ============
// 4 lanes per (b,q,h); lane c8 handles 8 channels via 16B loads. value row stride = vstride elems.
__global__ __launch_bounds__(256) void deform_sample_kernel(
    const float* __restrict__ ref, const float* __restrict__ off,
    const float* __restrict__ aw, const u16* __restrict__ value,
    u16* __restrict__ out, int Q, int vstride) {
  int g = blockIdx.x * 256 + threadIdx.x;
  int unit = g >> 2;
  int c8 = g & 3;
  int h = unit & 7;
  int bq = unit >> 3;
  if (bq >= Bc * Q) return;
  int b = bq / Q;
  const int HWs[4] = {100, 50, 25, 13};
  const int starts[4] = {0, 10000, 12500, 13125};
  const float* refp = ref + (size_t)bq * 8;
  const float* offp = off + (size_t)bq * 256 + h * 32;
  const float* awp = aw + (size_t)bq * 128 + h * 16;
  const u16* vbase = value + (size_t)b * LENc * vstride + h * 32 + c8 * 8;
  float a[8] = {};
#pragma unroll
  for (int l = 0; l < 4; ++l) {
    int HW = HWs[l];
    float HWf = (float)HW;
    int st = starts[l];
    float rx = refp[l * 2 + 0], ry = refp[l * 2 + 1];
#pragma unroll
    for (int p = 0; p < 4; ++p) {
      float ox = offp[(l * 4 + p) * 2 + 0];
      float oy = offp[(l * 4 + p) * 2 + 1];
      float wgt = awp[l * 4 + p];
      float x = rx * HWf + ox - 0.5f;
      float y = ry * HWf + oy - 0.5f;
      float xf = floorf(x), yf = floorf(y);
      float wx = x - xf, wy = y - yf;
      int x0 = (int)xf, y0 = (int)yf;
      float w00 = (1.f - wx) * (1.f - wy) * wgt;
      float w10 = wx * (1.f - wy) * wgt;
      float w01 = (1.f - wx) * wy * wgt;
      float w11 = wx * wy * wgt;
      bool xi0 = (x0 >= 0) & (x0 < HW);
      bool xi1 = (x0 + 1 >= 0) & (x0 + 1 < HW);
      bool yi0 = (y0 >= 0) & (y0 < HW);
      bool yi1 = (y0 + 1 >= 0) & (y0 + 1 < HW);
      if (xi0 & yi0) {
        ushort8v s = *(const ushort8v*)(vbase + (size_t)(st + y0 * HW + x0) * vstride);
#pragma unroll
        for (int k = 0; k < 8; ++k) a[k] += w00 * bf2f(s[k]);
      }
      if (xi1 & yi0) {
        ushort8v s = *(const ushort8v*)(vbase + (size_t)(st + y0 * HW + x0 + 1) * vstride);
#pragma unroll
        for (int k = 0; k < 8; ++k) a[k] += w10 * bf2f(s[k]);
      }
      if (xi0 & yi1) {
        ushort8v s = *(const ushort8v*)(vbase + (size_t)(st + (y0 + 1) * HW + x0) * vstride);
#pragma unroll
        for (int k = 0; k < 8; ++k) a[k] += w01 * bf2f(s[k]);
      }
      if (xi1 & yi1) {
        ushort8v s = *(const ushort8v*)(vbase + (size_t)(st + (y0 + 1) * HW + x0 + 1) * vstride);
#pragma unroll
        for (int k = 0; k < 8; ++k) a[k] += w11 * bf2f(s[k]);
      }
    }
  }
  ushort8v o;
#pragma unroll
  for (int k = 0; k < 8; ++k) o[k] = f2bf(a[k]);
  *(ushort8v*)(out + (size_t)bq * 256 + h * 32 + c8 * 8) = o;
}

// ============ decoder self-attention core ============
__global__ __launch_bounds__(256) void mha_core_kernel(
    const float* __restrict__ qk, const float* __restrict__ v, u16* __restrict__ out) {
  __shared__ float sc[4][304];
  int wslot = threadIdx.x >> 6;
  int lane = threadIdx.x & 63;
  int w = blockIdx.x * 4 + wslot;
  if (w >= Bc * NHc * NQc) return;
  int b = w / (NHc * NQc);
  int rem = w % (NHc * NQc);
  int h = rem / NQc;
  int qi = rem % NQc;
  const float scale = 0.1767766952966369f;
  float qv[32];
  const float* qptr = qk + ((size_t)(b * NQc + qi)) * 512 + h * 32;
#pragma unroll
  for (int d = 0; d < 32; ++d) qv[d] = qptr[d];
  float mx = -1e30f;
  for (int j = lane; j < NQc; j += 64) {
    const float* kptr = qk + ((size_t)(b * NQc + j)) * 512 + 256 + h * 32;
    float s = 0.f;
#pragma unroll
    for (int d = 0; d < 32; ++d) s += qv[d] * kptr[d];
    s *= scale;
    sc[wslot][j] = s;
    mx = fmaxf(mx, s);
  }
#pragma unroll
  for (int o = 32; o > 0; o >>= 1) mx = fmaxf(mx, __shfl_xor(mx, o, 64));
  float se = 0.f;
  for (int j = lane; j < NQc; j += 64) {
    float e = expf(sc[wslot][j] - mx);
    sc[wslot][j] = e;
    se += e;
  }
#pragma unroll
  for (int o = 32; o > 0; o >>= 1) se += __shfl_xor(se, o, 64);
  float inv = 1.f / se;
  if (lane < 32) {
    int d = lane;
    float acc = 0.f;
    for (int j = 0; j < NQc; ++j)
      acc += sc[wslot][j] * v[((size_t)(b * NQc + j)) * 256 + h * 32 + d];
    out[((size_t)(b * NQc + qi)) * 256 + h * 32 + d] = f2bf(acc * inv);
  }
}

// ============ host ============
static inline int cdiv_i(int a, int b) { return (a + b - 1) / b; }

#define WE_OFF   0
#define WE_AW    393216
#define WE_VAL   589824
#define WE_OUT   983040
#define WE_F1    1376256
#define WE_F2    2949120
#define WD_SAIN  4521984
#define WD_SAOUT 5701632
#define WD_OFF   6094848
#define WD_AW    6488064
#define WD_VAL   6684672
#define WD_OUT   7077888
#define WD_F1    7471104
#define WD_F2    9043968
#define W_TOTAL  10616832

extern "C" void kernel_launch(void* const* d_in, const int* in_sizes, int n_in,
                              void* d_out, int out_size, void* d_ws, size_t ws_size,
                              hipStream_t stream) {
  (void)in_sizes; (void)n_in;
  const float* src_p = (const float*)d_in[0];
  const float* pos_p = (const float*)d_in[1];
  const float* qe_p = (const float*)d_in[2];
  const float* vr_p = (const float*)d_in[3];
  const float* e_off_w = (const float*)d_in[4];  const float* e_off_b = (const float*)d_in[5];
  const float* e_aw_w = (const float*)d_in[6];   const float* e_aw_b = (const float*)d_in[7];
  const float* e_val_w = (const float*)d_in[8];  const float* e_val_b = (const float*)d_in[9];
  const float* e_out_w = (const float*)d_in[10]; const float* e_out_b = (const float*)d_in[11];
  const float* e_f1_w = (const float*)d_in[12];  const float* e_f1_b = (const float*)d_in[13];
  const float* e_f2_w = (const float*)d_in[14];  const float* e_f2_b = (const float*)d_in[15];
  const float* d_sa_in_w = (const float*)d_in[16];  const float* d_sa_in_b = (const float*)d_in[17];
  const float* d_sa_out_w = (const float*)d_in[18]; const float* d_sa_out_b = (const float*)d_in[19];
  const float* d_off_w = (const float*)d_in[20]; const float* d_off_b = (const float*)d_in[21];
  const float* d_aw_w = (const float*)d_in[22];  const float* d_aw_b = (const float*)d_in[23];
  const float* d_val_w = (const float*)d_in[24]; const float* d_val_b = (const float*)d_in[25];
  const float* d_out_w = (const float*)d_in[26]; const float* d_out_b = (const float*)d_in[27];
  const float* d_f1_w = (const float*)d_in[28];  const float* d_f1_b = (const float*)d_in[29];
  const float* d_f2_w = (const float*)d_in[30];  const float* d_f2_b = (const float*)d_in[31];
  const float* ref_w = (const float*)d_in[32];   const float* ref_b = (const float*)d_in[33];
  const float* e_ln1_g = (const float*)d_in[34]; const float* e_ln1_b = (const float*)d_in[35];
  const float* e_ln2_g = (const float*)d_in[36]; const float* e_ln2_b = (const float*)d_in[37];
  const float* d_ln1_g = (const float*)d_in[38]; const float* d_ln1_b = (const float*)d_in[39];
  const float* d_ln2_g = (const float*)d_in[40]; const float* d_ln2_b = (const float*)d_in[41];
  const float* d_ln3_g = (const float*)d_in[42]; const float* d_ln3_b = (const float*)d_in[43];

  const size_t BLC = (size_t)Bc * LENc * Cc;  // 6,806,528
  float* ws = (float*)d_ws;

  // f32 buffers
  float* mem = ws;                       // BLC   (dead after encoder)
  float* bufA = mem + BLC;               // BLC   (dead after encoder)
  float* U = bufA + BLC;                 // 2.5*BLC floats (encoder-phase unions)
  float* encref = U + (5 * BLC / 2);
  float* qpos = encref + (size_t)Bc * LENc * 8;
  float* doutb = qpos + (size_t)NQc * Cc;
  float* qkb = doutb + (size_t)Bc * NQc * Cc;
  float* dvb = qkb + (size_t)Bc * NQc * 512;
  float* drefb = dvb + (size_t)Bc * NQc * Cc;
  float* doffb = drefb + (size_t)Bc * NQc * 8;
  float* dawb = doffb + (size_t)Bc * NQc * Cc;
  float* dproj = dawb + (size_t)Bc * NQc * 128;
  float* after = dproj + (size_t)Bc * NQc * Cc;
  // bf16 buffers
  u16* mem_bf = (u16*)after;
  u16* qbuf_bf = mem_bf + BLC;
  u16* dout_bf = qbuf_bf + (size_t)Bc * NQc * Cc;
  u16* dattn_bf = dout_bf + (size_t)Bc * NQc * Cc;
  u16* dhid_bf = dattn_bf + (size_t)Bc * NQc * Cc;
  u16* wbf = dhid_bf + (size_t)Bc * NQc * FFc;
  u16* bf_end = wbf + W_TOTAL;
  // encoder-phase union members (in U)
  float* offb = U;                                  // BLC f32
  float* awb = U + BLC;                             // BLC/2 f32
  u16* value_bf = (u16*)(U + 3 * BLC / 2);          // BLC u16
  u16* xattn_bf = (u16*)(U + 2 * BLC);              // BLC u16
  u16* hid_bf = (u16*)U;                            // encoder FFN phase
  // decoder-phase: 6-layer batched value projections, overlaps mem/bufA/U-start (all dead)
  u16* value6_bf = (u16*)ws;                        // 6*BLC u16 = 81.7 MB < offset of encref

  size_t total_bytes = (size_t)((char*)bf_end - (char*)d_ws);
  if (ws_size < total_bytes) return;

  const int Mrows = Bc * LENc;  // 26588
  const int Mdec = Bc * NQc;    // 600
  const int EB = 256;

  // ---- convert all weights to bf16 ----
  WPack wp;
  wp.src[0] = e_off_w;   wp.src[1] = e_aw_w;    wp.src[2] = e_val_w;  wp.src[3] = e_out_w;
  wp.src[4] = e_f1_w;    wp.src[5] = e_f2_w;    wp.src[6] = d_sa_in_w; wp.src[7] = d_sa_out_w;
  wp.src[8] = d_off_w;   wp.src[9] = d_aw_w;    wp.src[10] = d_val_w; wp.src[11] = d_out_w;
  wp.src[12] = d_f1_w;   wp.src[13] = d_f2_w;
  const int offs[15] = {WE_OFF, WE_AW, WE_VAL, WE_OUT, WE_F1, WE_F2, WD_SAIN, WD_SAOUT,
                        WD_OFF, WD_AW, WD_VAL, WD_OUT, WD_F1, WD_F2, W_TOTAL};
  for (int k = 0; k < 15; ++k) wp.off4[k] = offs[k] / 4;
  convert_weights_kernel<<<cdiv_i(W_TOTAL / 4, EB), EB, 0, stream>>>(wp, wbf);

  auto gemm = [&](const u16* Xp, const u16* Wp, const float* bp, float* Yf, u16* Yb,
                  int M, int N, int K, int flags) {
    dim3 g(N / 128, cdiv_i(M, 128));
    gemm_mfma_kernel<<<g, dim3(256), 0, stream>>>(Xp, Wp, bp, Yf, Yb, M, N, K, flags);
  };
  auto gemm_s = [&](const u16* Xp, const u16* Wp, const float* bp, float* Yf, u16* Yb,
                    int M, int N, int K, int flags) {
    dim3 g(N / 64, cdiv_i(M, 64));
    gemm_small_kernel<<<g, dim3(256), 0, stream>>>(Xp, Wp, bp, Yf, Yb, M, N, K, flags);
  };

  conv_in_kernel<<<cdiv_i((int)BLC, EB), EB, 0, stream>>>(src_p, mem, mem_bf, (int)BLC);
  enc_ref_kernel<<<cdiv_i(Bc * LENc, EB), EB, 0, stream>>>(vr_p, encref);

  // ---- encoder ----
  for (int i = 0; i < Lc; ++i) {
    const size_t oW = (size_t)i * 256 * 256, oAW = (size_t)i * 128 * 256, oF = (size_t)i * 1024 * 256;
    const size_t o256 = (size_t)i * 256, o128 = (size_t)i * 128, o1024 = (size_t)i * 1024;
    add_pos_kernel<<<cdiv_i((int)BLC, EB), EB, 0, stream>>>(mem, pos_p, xattn_bf, (int)BLC);
    gemm(xattn_bf, wbf + WE_OFF + oW, e_off_b + o256, offb, nullptr, Mrows, 256, 256, 0);
    gemm(xattn_bf, wbf + WE_AW + oAW, e_aw_b + o128, awb, nullptr, Mrows, 128, 256, 0);
    softmax16_kernel<<<cdiv_i(Mrows * NHc, EB), EB, 0, stream>>>(awb, Mrows * NHc);
    gemm(mem_bf, wbf + WE_VAL + oW, e_val_b + o256, nullptr, value_bf, Mrows, 256, 256, 2);
    deform_sample_kernel<<<cdiv_i(Mrows * NHc * 4, EB), EB, 0, stream>>>(
        encref, offb, awb, value_bf, xattn_bf, LENc, 256);
    gemm(xattn_bf, wbf + WE_OUT + oW, e_out_b + o256, bufA, nullptr, Mrows, 256, 256, 0);
    add_ln_kernel<<<Mrows, 256, 0, stream>>>(mem, bufA, e_ln1_g + o256, e_ln1_b + o256, mem_bf, Mrows);
    gemm(mem_bf, wbf + WE_F1 + oF, e_f1_b + o1024, nullptr, hid_bf, Mrows, 1024, 256, 3);
    gemm(hid_bf, wbf + WE_F2 + oF, e_f2_b + o256, bufA, nullptr, Mrows, 256, 1024, 0);
    add_ln_kernel<<<Mrows, 256, 0, stream>>>(mem, bufA, e_ln2_g + o256, e_ln2_b + o256, mem_bf, Mrows);
  }

  // ---- batched decoder value projections (6 layers in one GEMM, N=1536) ----
  // d_val weights are contiguous per layer in wbf; d_val_b is (6,256) contiguous f32.
  gemm(mem_bf, wbf + WD_VAL, d_val_b, nullptr, value6_bf, Mrows, 6 * 256, 256, 2);

  // ---- decoder prep ----
  dec_init_kernel<<<cdiv_i(NQc * Cc, EB), EB, 0, stream>>>(qe_p, qpos, doutb, dout_bf);
  dec_ref_kernel<<<cdiv_i(NQc * 2, EB), EB, 0, stream>>>(qe_p, ref_w, ref_b, vr_p, drefb);

  const int ndec = Mdec * Cc;
  for (int i = 0; i < Lc; ++i) {
    const size_t oW = (size_t)i * 256 * 256, oAW = (size_t)i * 128 * 256, oF = (size_t)i * 1024 * 256;
    const size_t oSA = (size_t)i * 768 * 256;
    const size_t o256 = (size_t)i * 256, o128 = (size_t)i * 128, o1024 = (size_t)i * 1024, o768 = (size_t)i * 768;
    // self-attention
    add_bcast_bf_kernel<<<cdiv_i(ndec, EB), EB, 0, stream>>>(doutb, qpos, qbuf_bf, ndec, NQc * Cc);
    gemm_s(qbuf_bf, wbf + WD_SAIN + oSA, d_sa_in_b + o768, qkb, nullptr, Mdec, 512, 256, 0);
    gemm_s(dout_bf, wbf + WD_SAIN + oSA + (size_t)512 * 256, d_sa_in_b + o768 + 512, dvb, nullptr, Mdec, 256, 256, 0);
    mha_core_kernel<<<Bc * NHc * NQc / 4, 256, 0, stream>>>(qkb, dvb, dattn_bf);
    gemm_s(dattn_bf, wbf + WD_SAOUT + oW, d_sa_out_b + o256, dproj, nullptr, Mdec, 256, 256, 0);
    add_ln_kernel<<<Mdec, 256, 0, stream>>>(doutb, dproj, d_ln2_g + o256, d_ln2_b + o256, dout_bf, Mdec);
    // cross (deformable) attention
    add_bcast_bf_kernel<<<cdiv_i(ndec, EB), EB, 0, stream>>>(doutb, qpos, qbuf_bf, ndec, NQc * Cc);
    gemm_s(qbuf_bf, wbf + WD_OFF + oW, d_off_b + o256, doffb, nullptr, Mdec, 256, 256, 0);
    gemm_s(qbuf_bf, wbf + WD_AW + oAW, d_aw_b + o128, dawb, nullptr, Mdec, 128, 256, 0);
    softmax16_kernel<<<cdiv_i(Mdec * NHc, EB), EB, 0, stream>>>(dawb, Mdec * NHc);
    deform_sample_kernel<<<cdiv_i(Mdec * NHc * 4, EB), EB, 0, stream>>>(
        drefb, doffb, dawb, value6_bf + (size_t)i * 256, dattn_bf, NQc, 6 * 256);
    gemm_s(dattn_bf, wbf + WD_OUT + oW, d_out_b + o256, dproj, nullptr, Mdec, 256, 256, 0);
    add_ln_kernel<<<Mdec, 256, 0, stream>>>(doutb, dproj, d_ln1_g + o256, d_ln1_b + o256, dout_bf, Mdec);
    // FFN
    gemm_s(dout_bf, wbf + WD_F1 + oF, d_f1_b + o1024, nullptr, dhid_bf, Mdec, 1024, 256, 3);
    gemm_s(dhid_bf, wbf + WD_F2 + oF, d_f2_b + o256, dproj, nullptr, Mdec, 256, 1024, 0);
    add_ln_kernel<<<Mdec, 256, 0, stream>>>(doutb, dproj, d_ln3_g + o256, d_ln3_b + o256, dout_bf, Mdec);
  }

  store_f32_kernel<<<cdiv_i(out_size, EB), EB, 0, stream>>>(doutb, (float*)d_out, out_size);
}